// Round 7
// baseline (268.035 us; speedup 1.0000x reference)
//
#include <hip/hip_runtime.h>

#define T_IN   1048576
#define T_OUT  1048564              // T_IN - 12 (valid 5-tap then valid 9-tap)
#define QPR    262141               // output quads per row (T_OUT/4)
#define NROWS  32
#define NT     8                    // tiles per block
#define QPB    (256 * NT)           // 2048 quads per block
#define BPR    128                  // 128 * 2048 = 262144 >= QPR
#define NQUADS 8388512u             // 32 * T_OUT / 4 (exact)
#define CPYSTRIDE (2048u * 256u)

typedef float v4f __attribute__((ext_vector_type(4)));

__device__ __forceinline__ void compose13(const float* __restrict__ fd,
                                          const float* __restrict__ gs,
                                          float c[13])
{
    float f[5], g[9];
#pragma unroll
    for (int i = 0; i < 5; ++i) f[i] = fd[i];
#pragma unroll
    for (int j = 0; j < 9; ++j) g[j] = gs[j];
#pragma unroll
    for (int k = 0; k < 13; ++k) c[k] = 0.0f;
#pragma unroll
    for (int i = 0; i < 5; ++i)
#pragma unroll
        for (int j = 0; j < 9; ++j) c[i + j] = fmaf(f[i], g[j], c[i + j]);
}

// ---------------------------------------------------------------------------
// Dispatch 1 — CONTROL: known-good copy-bench structure (m13 pattern,
// 6.29 TB/s reference). Output garbage; dispatch 2 overwrites everything.
// Measures this session's true streaming ceiling on these buffers.
// ---------------------------------------------------------------------------
__global__ __launch_bounds__(256) void copy_ctrl(
    const float* __restrict__ x, float* __restrict__ out)
{
    const v4f* __restrict__ xq = reinterpret_cast<const v4f*>(x);
    v4f*       __restrict__ oq = reinterpret_cast<v4f*>(out);
    unsigned k = blockIdx.x * 256u + threadIdx.x;
#pragma unroll 1
    for (; k < NQUADS; k += CPYSTRIDE)
        oq[k] = xq[k];
}

// ---------------------------------------------------------------------------
// Dispatch 2 — v5: LDS halo-sharing (1 global load + 1 store per 16B output,
// no redundant global reads) + NT-tile persistent blocks with LDS
// double-buffer: tile t+1's global load is issued before tile t's compute,
// so its latency hides under 52 FMA + 3 LDS reads + store. One barrier per
// 1KB-output tile; write/read buffers alternate (no WAR across the barrier).
// ---------------------------------------------------------------------------
__global__ __launch_bounds__(256) void pinn_fused_conv13_v5(
    const float* __restrict__ x,
    const float* __restrict__ fd,     // 5 taps (already scaled by 1/h^2)
    const float* __restrict__ gs,     // 9 taps
    float* __restrict__ out)
{
    __shared__ float lds[2][1040];    // 2 x (256*4 main + 16 halo)

    const int r = blockIdx.y;
    const int b = blockIdx.x;
    const int t = threadIdx.x;
    const int qb0 = b * QPB;          // block's first quad

    const float* __restrict__ xrow = x + (size_t)r * T_IN;
    float*       __restrict__ orow = out + (size_t)r * T_OUT;

    float c[13];
    compose13(fd, gs, c);

    // ---- prologue: stage tile 0 ----
    // main load spans [in0 + 16*tid, +16) bytes; max = in0 + 4096 B = T_IN edge. safe.
    const int in0 = qb0 << 2;
    v4f mv = *reinterpret_cast<const v4f*>(xrow + in0 + 4 * t);
    if (t < 4) {
        v4f hv = (v4f){0.f, 0.f, 0.f, 0.f};
        if (in0 + 1024 + 4 * t + 4 <= T_IN)
            hv = *reinterpret_cast<const v4f*>(xrow + in0 + 1024 + 4 * t);
        *reinterpret_cast<v4f*>(&lds[0][1024 + 4 * t]) = hv;
    }
    *reinterpret_cast<v4f*>(&lds[0][4 * t]) = mv;
    __syncthreads();

    float* cur = &lds[0][0];
    float* nxt = &lds[1][0];

#pragma unroll 1
    for (int tt = 0; tt < NT; ++tt) {
        const int qb = qb0 + (tt << 8);
        const bool more = (tt + 1 < NT);      // block-uniform

        // ---- prefetch tile tt+1 (in flight across the whole compute) ----
        v4f mvn = (v4f){0.f, 0.f, 0.f, 0.f};
        v4f hvn = (v4f){0.f, 0.f, 0.f, 0.f};
        if (more) {
            const int in1 = (qb + 256) << 2;
            mvn = *reinterpret_cast<const v4f*>(xrow + in1 + 4 * t);
            if (t < 4 && in1 + 1024 + 4 * t + 4 <= T_IN)
                hvn = *reinterpret_cast<const v4f*>(xrow + in1 + 1024 + 4 * t);
        }

        // ---- compute tile tt from cur (own quad already in mv) ----
        const int q = qb + t;
        if (q < QPR) {
            const v4f w1 = *reinterpret_cast<const v4f*>(cur + 4 * t + 4);
            const v4f w2 = *reinterpret_cast<const v4f*>(cur + 4 * t + 8);
            const v4f w3 = *reinterpret_cast<const v4f*>(cur + 4 * t + 12);
            const float a[16] = {mv[0], mv[1], mv[2], mv[3],
                                 w1[0], w1[1], w1[2], w1[3],
                                 w2[0], w2[1], w2[2], w2[3],
                                 w3[0], w3[1], w3[2], w3[3]};
            v4f ov;
#pragma unroll
            for (int j = 0; j < 4; ++j) {
                float s = c[0] * a[j];
#pragma unroll
                for (int k = 1; k < 13; ++k) s = fmaf(c[k], a[j + k], s);
                ov[j] = s;
            }
            __builtin_nontemporal_store(
                ov, reinterpret_cast<v4f*>(orow + ((size_t)q << 2)));
        }

        // ---- publish tile tt+1, swap buffers ----
        if (more) {
            *reinterpret_cast<v4f*>(nxt + 4 * t) = mvn;
            if (t < 4)
                *reinterpret_cast<v4f*>(nxt + 1024 + 4 * t) = hvn;
            __syncthreads();
            mv = mvn;
            float* tmp = cur; cur = nxt; nxt = tmp;
        }
    }
}

extern "C" void kernel_launch(void* const* d_in, const int* in_sizes, int n_in,
                              void* d_out, int out_size, void* d_ws, size_t ws_size,
                              hipStream_t stream) {
    const float* x  = (const float*)d_in[0];
    const float* fd = (const float*)d_in[1];
    const float* gs = (const float*)d_in[2];
    float* out = (float*)d_out;

    // CONTROL first (its output is fully overwritten by the real kernel).
    copy_ctrl<<<2048, 256, 0, stream>>>(x, out);

    // Real computation.
    dim3 grid(BPR, NROWS);   // 4096 blocks of 256 threads, 8 tiles each
    pinn_fused_conv13_v5<<<grid, 256, 0, stream>>>(x, fd, gs, out);
}